// Round 2
// baseline (126.248 us; speedup 1.0000x reference)
//
#include <hip/hip_runtime.h>
#include <hip/hip_bf16.h>

#define SPATIAL_SCALE 0.125f
#define POOLED 7
#define PART 7
#define SAMPLES 4
#define TRANS_STD 0.1f

#define B_DIM 4
#define C_DIM 256
#define H_DIM 64
#define W_DIM 64

// ---------------------------------------------------------------------------
// NCHW -> NHWC transpose: data[b][c][y][x] -> data_t[b][y][x][c]
// Per batch it is a (C=256) x (HW=4096) matrix transpose. LDS 32x32 tiles,
// +1 pad to kill bank conflicts; both global read and write coalesced.
// ---------------------------------------------------------------------------
#define TS 32
__global__ __launch_bounds__(256) void nchw_to_nhwc(const float* __restrict__ in,
                                                    float* __restrict__ out) {
    __shared__ float tile[TS][TS + 1];
    const int b   = blockIdx.z;
    const int hw0 = blockIdx.x * TS;   // position along HW (4096)
    const int c0  = blockIdx.y * TS;   // position along C (256)
    const int tx  = threadIdx.x;       // 0..31
    const int ty  = threadIdx.y;       // 0..7

    const float* inb  = in  + (size_t)b * C_DIM * (H_DIM * W_DIM);
    float*       outb = out + (size_t)b * (H_DIM * W_DIM) * C_DIM;

    // load: tile[c_local][hw_local], coalesced along hw
    #pragma unroll
    for (int i = ty; i < TS; i += 8) {
        tile[i][tx] = inb[(size_t)(c0 + i) * (H_DIM * W_DIM) + (hw0 + tx)];
    }
    __syncthreads();
    // store: out[hw][c], coalesced along c
    #pragma unroll
    for (int i = ty; i < TS; i += 8) {
        outb[(size_t)(hw0 + i) * C_DIM + (c0 + tx)] = tile[tx][i];
    }
}

// ---------------------------------------------------------------------------
// Deformable RoI pooling. One block per (n, ph, pw); 256 threads = channels.
// Geometry (16 sample coords, bilinear weights, validity) is block-uniform;
// each thread computes it redundantly (cheap) and does 4 coalesced tap loads
// per valid sample.
// NHWC=true : src is data_t[b][y][x][c]  (coalesced taps, fast path)
// NHWC=false: src is data[b][c][y][x]    (fallback if ws too small)
// ---------------------------------------------------------------------------
template <bool NHWC>
__global__ __launch_bounds__(256) void deform_roi_pool(const float* __restrict__ src,
                                                       const float* __restrict__ rois,
                                                       const float* __restrict__ offset,
                                                       float* __restrict__ out,
                                                       int N) {
    const int blk = blockIdx.x;
    const int n   = blk / (POOLED * POOLED);
    const int bin = blk % (POOLED * POOLED);
    const int ph  = bin / POOLED;
    const int pw  = bin % POOLED;
    const int c   = threadIdx.x;
    if (n >= N) return;

    const float* roi = rois + (size_t)n * 5;
    const int b = (int)roi[0];

    // rounded roi box in feature coords (round-half-even to match jnp.round)
    const float roi_sw = rintf(roi[1]) * SPATIAL_SCALE - 0.5f;
    const float roi_sh = rintf(roi[2]) * SPATIAL_SCALE - 0.5f;
    const float roi_ew = (rintf(roi[3]) + 1.0f) * SPATIAL_SCALE - 0.5f;
    const float roi_eh = (rintf(roi[4]) + 1.0f) * SPATIAL_SCALE - 0.5f;
    const float roi_w = fmaxf(roi_ew - roi_sw, 0.1f);
    const float roi_h = fmaxf(roi_eh - roi_sh, 0.1f);
    const float bin_w = roi_w / (float)POOLED;
    const float bin_h = roi_h / (float)POOLED;
    const float sub_w = bin_w / (float)SAMPLES;
    const float sub_h = bin_h / (float)SAMPLES;

    // part indices (identical to ph/pw for P==PART==7, but replicate ref math)
    int part_h = (int)floorf(((float)ph / (float)POOLED) * (float)PART);
    int part_w = (int)floorf(((float)pw / (float)POOLED) * (float)PART);
    part_h = min(max(part_h, 0), PART - 1);
    part_w = min(max(part_w, 0), PART - 1);

    const float tx = offset[(((size_t)n * 2 + 0) * PART + part_h) * PART + part_w] * TRANS_STD;
    const float ty = offset[(((size_t)n * 2 + 1) * PART + part_h) * PART + part_w] * TRANS_STD;

    const float wstart = (float)pw * bin_w + roi_sw + tx * roi_w;
    const float hstart = (float)ph * bin_h + roi_sh + ty * roi_h;

    float sum = 0.0f;
    int cnt = 0;

    #pragma unroll
    for (int sh = 0; sh < SAMPLES; ++sh) {
        const float h = hstart + (float)sh * sub_h;
        #pragma unroll
        for (int sw = 0; sw < SAMPLES; ++sw) {
            const float w = wstart + (float)sw * sub_w;
            const bool valid = (w > -0.5f) && (w < (float)W_DIM - 0.5f) &&
                               (h > -0.5f) && (h < (float)H_DIM - 0.5f);
            if (!valid) continue;   // block-uniform branch
            ++cnt;
            const float wc = fminf(fmaxf(w, 0.0f), (float)(W_DIM - 1));
            const float hc = fminf(fmaxf(h, 0.0f), (float)(H_DIM - 1));
            const int x0 = (int)floorf(wc);
            const int y0 = (int)floorf(hc);
            const int x1 = min(x0 + 1, W_DIM - 1);
            const int y1 = min(y0 + 1, H_DIM - 1);
            const float dx = wc - (float)x0;
            const float dy = hc - (float)y0;

            float v00, v01, v10, v11;
            if (NHWC) {
                const size_t base = ((size_t)b * H_DIM) * W_DIM * C_DIM;
                v00 = src[base + ((size_t)y0 * W_DIM + x0) * C_DIM + c];
                v01 = src[base + ((size_t)y0 * W_DIM + x1) * C_DIM + c];
                v10 = src[base + ((size_t)y1 * W_DIM + x0) * C_DIM + c];
                v11 = src[base + ((size_t)y1 * W_DIM + x1) * C_DIM + c];
            } else {
                const size_t base = ((size_t)b * C_DIM + c) * (H_DIM * W_DIM);
                v00 = src[base + (size_t)y0 * W_DIM + x0];
                v01 = src[base + (size_t)y0 * W_DIM + x1];
                v10 = src[base + (size_t)y1 * W_DIM + x0];
                v11 = src[base + (size_t)y1 * W_DIM + x1];
            }
            sum += (1.0f - dx) * (1.0f - dy) * v00
                 + (1.0f - dx) * dy          * v10
                 + dx          * (1.0f - dy) * v01
                 + dx          * dy          * v11;
        }
    }

    const float res = (cnt > 0) ? sum / (float)cnt : 0.0f;
    out[(((size_t)n * C_DIM + c) * POOLED + ph) * POOLED + pw] = res;
}

extern "C" void kernel_launch(void* const* d_in, const int* in_sizes, int n_in,
                              void* d_out, int out_size, void* d_ws, size_t ws_size,
                              hipStream_t stream) {
    const float* data   = (const float*)d_in[0];
    const float* rois   = (const float*)d_in[1];
    const float* offset = (const float*)d_in[2];
    float* out = (float*)d_out;
    const int N = in_sizes[1] / 5;

    const size_t t_bytes = (size_t)B_DIM * C_DIM * H_DIM * W_DIM * sizeof(float);

    if (ws_size >= t_bytes) {
        float* data_t = (float*)d_ws;
        dim3 tb(32, 8, 1);
        dim3 tg((H_DIM * W_DIM) / TS, C_DIM / TS, B_DIM);
        nchw_to_nhwc<<<tg, tb, 0, stream>>>(data, data_t);
        deform_roi_pool<true><<<N * POOLED * POOLED, C_DIM, 0, stream>>>(
            data_t, rois, offset, out, N);
    } else {
        deform_roi_pool<false><<<N * POOLED * POOLED, C_DIM, 0, stream>>>(
            data, rois, offset, out, N);
    }
}

// Round 3
// 112.169 us; speedup vs baseline: 1.1255x; 1.1255x over previous
//
#include <hip/hip_runtime.h>
#include <hip/hip_bf16.h>

#define SPATIAL_SCALE 0.125f
#define POOLED 7
#define PART 7
#define SAMPLES 4
#define TRANS_STD 0.1f

#define B_DIM 4
#define C_DIM 256
#define H_DIM 64
#define W_DIM 64
#define BINS (POOLED * POOLED)   // 49
#define C4 (C_DIM / 4)           // 64 float4 groups

__device__ __forceinline__ float rfl_f(float x) {
    return __int_as_float(__builtin_amdgcn_readfirstlane(__float_as_int(x)));
}

// ---------------------------------------------------------------------------
// NCHW -> NHWC transpose: data[b][c][y][x] -> data_t[b][y][x][c]
// ---------------------------------------------------------------------------
#define TS 32
__global__ __launch_bounds__(256) void nchw_to_nhwc(const float* __restrict__ in,
                                                    float* __restrict__ out) {
    __shared__ float tile[TS][TS + 1];
    const int b   = blockIdx.z;
    const int hw0 = blockIdx.x * TS;
    const int c0  = blockIdx.y * TS;
    const int tx  = threadIdx.x;
    const int ty  = threadIdx.y;

    const float* inb  = in  + (size_t)b * C_DIM * (H_DIM * W_DIM);
    float*       outb = out + (size_t)b * (H_DIM * W_DIM) * C_DIM;

    #pragma unroll
    for (int i = ty; i < TS; i += 8)
        tile[i][tx] = inb[(size_t)(c0 + i) * (H_DIM * W_DIM) + (hw0 + tx)];
    __syncthreads();
    #pragma unroll
    for (int i = ty; i < TS; i += 8)
        outb[(size_t)(hw0 + i) * C_DIM + (c0 + tx)] = tile[tx][i];
}

// ---------------------------------------------------------------------------
// Pool v2: one WAVE (64 threads) per (n, bin). Lane = 4 channels (float4,
// NHWC-contiguous). Geometry is wave-uniform -> readfirstlane pushes sample
// indices/weights into SGPRs so tap addressing is scalar; VALU does only the
// bilinear FMAs. Writes tmp[n][bin][c]: 1 KB fully-coalesced per wave, each
// cache line owned by exactly one block (kills the 7.8x write amplification
// seen in round 2: WRITE_SIZE 99.5 MB vs 12.8 MB ideal).
// ---------------------------------------------------------------------------
__global__ __launch_bounds__(64) void deform_roi_pool_v2(const float4* __restrict__ src4,
                                                         const float* __restrict__ rois,
                                                         const float* __restrict__ offset,
                                                         float4* __restrict__ tmp4,
                                                         int N) {
    const int blk = blockIdx.x;
    const int n   = blk / BINS;
    const int bin = blk % BINS;
    const int ph  = bin / POOLED;
    const int pw  = bin % POOLED;
    const int lane = threadIdx.x;   // 0..63, channels 4*lane..4*lane+3
    if (n >= N) return;

    const float* roi = rois + (size_t)n * 5;
    const int b = __builtin_amdgcn_readfirstlane((int)roi[0]);

    const float roi_sw = rintf(roi[1]) * SPATIAL_SCALE - 0.5f;
    const float roi_sh = rintf(roi[2]) * SPATIAL_SCALE - 0.5f;
    const float roi_ew = (rintf(roi[3]) + 1.0f) * SPATIAL_SCALE - 0.5f;
    const float roi_eh = (rintf(roi[4]) + 1.0f) * SPATIAL_SCALE - 0.5f;
    const float roi_w = fmaxf(roi_ew - roi_sw, 0.1f);
    const float roi_h = fmaxf(roi_eh - roi_sh, 0.1f);
    const float bin_w = roi_w / (float)POOLED;
    const float bin_h = roi_h / (float)POOLED;
    const float sub_w = bin_w / (float)SAMPLES;
    const float sub_h = bin_h / (float)SAMPLES;

    int part_h = (int)floorf(((float)ph / (float)POOLED) * (float)PART);
    int part_w = (int)floorf(((float)pw / (float)POOLED) * (float)PART);
    part_h = min(max(part_h, 0), PART - 1);
    part_w = min(max(part_w, 0), PART - 1);

    const float tx = offset[(((size_t)n * 2 + 0) * PART + part_h) * PART + part_w] * TRANS_STD;
    const float ty = offset[(((size_t)n * 2 + 1) * PART + part_h) * PART + part_w] * TRANS_STD;

    const float wstart = (float)pw * bin_w + roi_sw + tx * roi_w;
    const float hstart = (float)ph * bin_h + roi_sh + ty * roi_h;

    const float4* baseb = src4 + (size_t)b * (H_DIM * W_DIM) * C4;

    float4 acc = make_float4(0.f, 0.f, 0.f, 0.f);
    int cnt = 0;

    #pragma unroll
    for (int sh = 0; sh < SAMPLES; ++sh) {
        const float h = hstart + (float)sh * sub_h;
        #pragma unroll
        for (int sw = 0; sw < SAMPLES; ++sw) {
            const float w = wstart + (float)sw * sub_w;
            const bool valid = (w > -0.5f) && (w < (float)W_DIM - 0.5f) &&
                               (h > -0.5f) && (h < (float)H_DIM - 0.5f);
            if (!valid) continue;   // wave-uniform branch
            ++cnt;
            const float wc = fminf(fmaxf(w, 0.0f), (float)(W_DIM - 1));
            const float hc = fminf(fmaxf(h, 0.0f), (float)(H_DIM - 1));
            const int x0 = (int)floorf(wc);
            const int y0 = (int)floorf(hc);
            const int x1 = min(x0 + 1, W_DIM - 1);
            const int y1 = min(y0 + 1, H_DIM - 1);
            const float dx = wc - (float)x0;
            const float dy = hc - (float)y0;

            // wave-uniform -> SGPRs (scalar address path)
            const int i00 = __builtin_amdgcn_readfirstlane(y0 * W_DIM + x0);
            const int i01 = __builtin_amdgcn_readfirstlane(y0 * W_DIM + x1);
            const int i10 = __builtin_amdgcn_readfirstlane(y1 * W_DIM + x0);
            const int i11 = __builtin_amdgcn_readfirstlane(y1 * W_DIM + x1);
            const float w00 = rfl_f((1.0f - dx) * (1.0f - dy));
            const float w10 = rfl_f((1.0f - dx) * dy);
            const float w01 = rfl_f(dx * (1.0f - dy));
            const float w11 = rfl_f(dx * dy);

            const float4 v00 = baseb[(size_t)i00 * C4 + lane];
            const float4 v01 = baseb[(size_t)i01 * C4 + lane];
            const float4 v10 = baseb[(size_t)i10 * C4 + lane];
            const float4 v11 = baseb[(size_t)i11 * C4 + lane];

            acc.x = fmaf(w11, v11.x, fmaf(w01, v01.x, fmaf(w10, v10.x, fmaf(w00, v00.x, acc.x))));
            acc.y = fmaf(w11, v11.y, fmaf(w01, v01.y, fmaf(w10, v10.y, fmaf(w00, v00.y, acc.y))));
            acc.z = fmaf(w11, v11.z, fmaf(w01, v01.z, fmaf(w10, v10.z, fmaf(w00, v00.z, acc.z))));
            acc.w = fmaf(w11, v11.w, fmaf(w01, v01.w, fmaf(w10, v10.w, fmaf(w00, v00.w, acc.w))));
        }
    }

    float4 res;
    if (cnt > 0) {
        const float inv = (float)cnt;
        res = make_float4(acc.x / inv, acc.y / inv, acc.z / inv, acc.w / inv);
    } else {
        res = make_float4(0.f, 0.f, 0.f, 0.f);
    }
    tmp4[(size_t)blk * 64 + lane] = res;   // [n][bin][c] coalesced 1 KB/wave
}

// ---------------------------------------------------------------------------
// tmp[n][bin][c] -> out[n][c][ph][pw]. Block = (channel-quarter q, n).
// LDS 49x65 (pad 65: bank = (bin + c) % 32 -> conflict-free-ish both phases).
// Both global read and global write fully coalesced.
// ---------------------------------------------------------------------------
__global__ __launch_bounds__(256) void layout_out(const float* __restrict__ tmp,
                                                  float* __restrict__ out) {
    __shared__ float lds[BINS * 65];
    const int q = blockIdx.x;   // 0..3 -> channels q*64..q*64+63
    const int n = blockIdx.y;
    const int t = threadIdx.x;

    const float* tn = tmp + (size_t)n * BINS * C_DIM + q * 64;
    // load: j = bin*64 + c_local, coalesced over c
    for (int j = t; j < BINS * 64; j += 256) {
        const int bin = j >> 6;
        const int c   = j & 63;
        lds[bin * 65 + c] = tn[(size_t)bin * C_DIM + c];
    }
    __syncthreads();
    // store: flat j = c_local*49 + bin, coalesced over j
    float* on = out + (size_t)n * C_DIM * BINS + (size_t)q * 64 * BINS;
    for (int j = t; j < 64 * BINS; j += 256) {
        const int c   = j / BINS;
        const int bin = j - c * BINS;
        on[j] = lds[bin * 65 + c];
    }
}

// ---------------------------------------------------------------------------
// Fallback (round-2 behavior): block per (n,bin) x 256 ch, direct NCHW/NHWC.
// ---------------------------------------------------------------------------
template <bool NHWC>
__global__ __launch_bounds__(256) void deform_roi_pool(const float* __restrict__ src,
                                                       const float* __restrict__ rois,
                                                       const float* __restrict__ offset,
                                                       float* __restrict__ out,
                                                       int N) {
    const int blk = blockIdx.x;
    const int n   = blk / BINS;
    const int bin = blk % BINS;
    const int ph  = bin / POOLED;
    const int pw  = bin % POOLED;
    const int c   = threadIdx.x;
    if (n >= N) return;

    const float* roi = rois + (size_t)n * 5;
    const int b = (int)roi[0];

    const float roi_sw = rintf(roi[1]) * SPATIAL_SCALE - 0.5f;
    const float roi_sh = rintf(roi[2]) * SPATIAL_SCALE - 0.5f;
    const float roi_ew = (rintf(roi[3]) + 1.0f) * SPATIAL_SCALE - 0.5f;
    const float roi_eh = (rintf(roi[4]) + 1.0f) * SPATIAL_SCALE - 0.5f;
    const float roi_w = fmaxf(roi_ew - roi_sw, 0.1f);
    const float roi_h = fmaxf(roi_eh - roi_sh, 0.1f);
    const float bin_w = roi_w / (float)POOLED;
    const float bin_h = roi_h / (float)POOLED;
    const float sub_w = bin_w / (float)SAMPLES;
    const float sub_h = bin_h / (float)SAMPLES;

    int part_h = (int)floorf(((float)ph / (float)POOLED) * (float)PART);
    int part_w = (int)floorf(((float)pw / (float)POOLED) * (float)PART);
    part_h = min(max(part_h, 0), PART - 1);
    part_w = min(max(part_w, 0), PART - 1);

    const float tx = offset[(((size_t)n * 2 + 0) * PART + part_h) * PART + part_w] * TRANS_STD;
    const float ty = offset[(((size_t)n * 2 + 1) * PART + part_h) * PART + part_w] * TRANS_STD;

    const float wstart = (float)pw * bin_w + roi_sw + tx * roi_w;
    const float hstart = (float)ph * bin_h + roi_sh + ty * roi_h;

    float sum = 0.0f;
    int cnt = 0;

    #pragma unroll
    for (int sh = 0; sh < SAMPLES; ++sh) {
        const float h = hstart + (float)sh * sub_h;
        #pragma unroll
        for (int sw = 0; sw < SAMPLES; ++sw) {
            const float w = wstart + (float)sw * sub_w;
            const bool valid = (w > -0.5f) && (w < (float)W_DIM - 0.5f) &&
                               (h > -0.5f) && (h < (float)H_DIM - 0.5f);
            if (!valid) continue;
            ++cnt;
            const float wc = fminf(fmaxf(w, 0.0f), (float)(W_DIM - 1));
            const float hc = fminf(fmaxf(h, 0.0f), (float)(H_DIM - 1));
            const int x0 = (int)floorf(wc);
            const int y0 = (int)floorf(hc);
            const int x1 = min(x0 + 1, W_DIM - 1);
            const int y1 = min(y0 + 1, H_DIM - 1);
            const float dx = wc - (float)x0;
            const float dy = hc - (float)y0;

            float v00, v01, v10, v11;
            if (NHWC) {
                const size_t base = ((size_t)b * H_DIM) * W_DIM * C_DIM;
                v00 = src[base + ((size_t)y0 * W_DIM + x0) * C_DIM + c];
                v01 = src[base + ((size_t)y0 * W_DIM + x1) * C_DIM + c];
                v10 = src[base + ((size_t)y1 * W_DIM + x0) * C_DIM + c];
                v11 = src[base + ((size_t)y1 * W_DIM + x1) * C_DIM + c];
            } else {
                const size_t base = ((size_t)b * C_DIM + c) * (H_DIM * W_DIM);
                v00 = src[base + (size_t)y0 * W_DIM + x0];
                v01 = src[base + (size_t)y0 * W_DIM + x1];
                v10 = src[base + (size_t)y1 * W_DIM + x0];
                v11 = src[base + (size_t)y1 * W_DIM + x1];
            }
            sum += (1.0f - dx) * (1.0f - dy) * v00
                 + (1.0f - dx) * dy          * v10
                 + dx          * (1.0f - dy) * v01
                 + dx          * dy          * v11;
        }
    }

    const float res = (cnt > 0) ? sum / (float)cnt : 0.0f;
    out[(((size_t)n * C_DIM + c) * POOLED + ph) * POOLED + pw] = res;
}

extern "C" void kernel_launch(void* const* d_in, const int* in_sizes, int n_in,
                              void* d_out, int out_size, void* d_ws, size_t ws_size,
                              hipStream_t stream) {
    const float* data   = (const float*)d_in[0];
    const float* rois   = (const float*)d_in[1];
    const float* offset = (const float*)d_in[2];
    float* out = (float*)d_out;
    const int N = in_sizes[1] / 5;

    const size_t nhwc_bytes = (size_t)B_DIM * C_DIM * H_DIM * W_DIM * sizeof(float);
    const size_t tmp_bytes  = (size_t)N * BINS * C_DIM * sizeof(float);

    if (ws_size >= nhwc_bytes + tmp_bytes) {
        float* data_t = (float*)d_ws;
        float* tmp    = (float*)((char*)d_ws + nhwc_bytes);
        dim3 tb(32, 8, 1);
        dim3 tg((H_DIM * W_DIM) / TS, C_DIM / TS, B_DIM);
        nchw_to_nhwc<<<tg, tb, 0, stream>>>(data, data_t);
        deform_roi_pool_v2<<<N * BINS, 64, 0, stream>>>(
            (const float4*)data_t, rois, offset, (float4*)tmp, N);
        layout_out<<<dim3(4, N, 1), 256, 0, stream>>>(tmp, out);
    } else if (ws_size >= nhwc_bytes) {
        float* data_t = (float*)d_ws;
        dim3 tb(32, 8, 1);
        dim3 tg((H_DIM * W_DIM) / TS, C_DIM / TS, B_DIM);
        nchw_to_nhwc<<<tg, tb, 0, stream>>>(data, data_t);
        deform_roi_pool<true><<<N * BINS, C_DIM, 0, stream>>>(
            data_t, rois, offset, out, N);
    } else {
        deform_roi_pool<false><<<N * BINS, C_DIM, 0, stream>>>(
            data, rois, offset, out, N);
    }
}

// Round 4
// 96.414 us; speedup vs baseline: 1.3094x; 1.1634x over previous
//
#include <hip/hip_runtime.h>
#include <hip/hip_bf16.h>

#define SPATIAL_SCALE 0.125f
#define POOLED 7
#define PART 7
#define SAMPLES 4
#define TRANS_STD 0.1f

#define B_DIM 4
#define C_DIM 256
#define H_DIM 64
#define W_DIM 64
#define BINS (POOLED * POOLED)   // 49
#define C4 (C_DIM / 4)           // 64 float4 groups

// ---------------------------------------------------------------------------
// NCHW -> NHWC transpose: data[b][c][y][x] -> data_t[b][y][x][c]
// ---------------------------------------------------------------------------
#define TS 32
__global__ __launch_bounds__(256) void nchw_to_nhwc(const float* __restrict__ in,
                                                    float* __restrict__ out) {
    __shared__ float tile[TS][TS + 1];
    const int b   = blockIdx.z;
    const int hw0 = blockIdx.x * TS;
    const int c0  = blockIdx.y * TS;
    const int tx  = threadIdx.x;
    const int ty  = threadIdx.y;

    const float* inb  = in  + (size_t)b * C_DIM * (H_DIM * W_DIM);
    float*       outb = out + (size_t)b * (H_DIM * W_DIM) * C_DIM;

    #pragma unroll
    for (int i = ty; i < TS; i += 8)
        tile[i][tx] = inb[(size_t)(c0 + i) * (H_DIM * W_DIM) + (hw0 + tx)];
    __syncthreads();
    #pragma unroll
    for (int i = ty; i < TS; i += 8)
        outb[(size_t)(hw0 + i) * C_DIM + (c0 + tx)] = tile[tx][i];
}

// ---------------------------------------------------------------------------
// Pool v3: separable weight aggregation. One wave per (n, bin); lane = 4
// channels (float4, NHWC). Key identity: validity/clip/bilinear weights
// factorize by axis, so
//   sum_over_16_samples(bilinear taps) == (sum_sh wy_vec) (x) (sum_sw wx_vec)
//   count == nvh * nvw
// exactly. Footprint per axis <= 4 cells (sample span <= 1.6 px + 1 tap).
// Round-3 pool did 64 float4 tap loads/wave; this does one load per distinct
// footprint pixel (typ. 4-9, max 16) — ~7x fewer L1 line-requests, which is
// the pipe the round-3 kernel was bound on.
// ---------------------------------------------------------------------------
__global__ __launch_bounds__(64) void deform_roi_pool_v3(const float4* __restrict__ src4,
                                                         const float* __restrict__ rois,
                                                         const float* __restrict__ offset,
                                                         float4* __restrict__ tmp4,
                                                         int N) {
    const int blk = blockIdx.x;
    const int n   = blk / BINS;
    const int bin = blk % BINS;
    const int ph  = bin / POOLED;
    const int pw  = bin % POOLED;
    const int lane = threadIdx.x;
    if (n >= N) return;

    const float* roi = rois + (size_t)n * 5;
    const int b = (int)roi[0];

    const float roi_sw = rintf(roi[1]) * SPATIAL_SCALE - 0.5f;
    const float roi_sh = rintf(roi[2]) * SPATIAL_SCALE - 0.5f;
    const float roi_ew = (rintf(roi[3]) + 1.0f) * SPATIAL_SCALE - 0.5f;
    const float roi_eh = (rintf(roi[4]) + 1.0f) * SPATIAL_SCALE - 0.5f;
    const float roi_w = fmaxf(roi_ew - roi_sw, 0.1f);
    const float roi_h = fmaxf(roi_eh - roi_sh, 0.1f);
    const float bin_w = roi_w / (float)POOLED;
    const float bin_h = roi_h / (float)POOLED;
    const float sub_w = bin_w / (float)SAMPLES;
    const float sub_h = bin_h / (float)SAMPLES;

    int part_h = (int)floorf(((float)ph / (float)POOLED) * (float)PART);
    int part_w = (int)floorf(((float)pw / (float)POOLED) * (float)PART);
    part_h = min(max(part_h, 0), PART - 1);
    part_w = min(max(part_w, 0), PART - 1);

    const float tx = offset[(((size_t)n * 2 + 0) * PART + part_h) * PART + part_w] * TRANS_STD;
    const float ty = offset[(((size_t)n * 2 + 1) * PART + part_h) * PART + part_w] * TRANS_STD;

    const float wstart = (float)pw * bin_w + roi_sw + tx * roi_w;
    const float hstart = (float)ph * bin_h + roi_sh + ty * roi_h;

    // ---- per-axis aggregated weights (wave-uniform scalar work) ----
    // w (resp. h) is strictly increasing in sw (sub_w>0), so the first valid
    // sample's x0 is the footprint minimum; valid range is contiguous.
    float Wx[4] = {0.f, 0.f, 0.f, 0.f};
    int xmin = 0, nvw = 0;
    #pragma unroll
    for (int sw = 0; sw < SAMPLES; ++sw) {
        const float w = wstart + (float)sw * sub_w;
        if (w > -0.5f && w < (float)W_DIM - 0.5f) {
            const float wc = fminf(fmaxf(w, 0.0f), (float)(W_DIM - 1));
            const int x0 = (int)floorf(wc);
            const int x1 = min(x0 + 1, W_DIM - 1);
            const float dx = wc - (float)x0;
            if (nvw == 0) xmin = x0;
            ++nvw;
            const int i0 = x0 - xmin;   // 0..2
            const int i1 = x1 - xmin;   // 0..3 (== i0 on clamp collapse)
            const float w0 = 1.0f - dx;
            Wx[0] += (i0 == 0 ? w0 : 0.f) + (i1 == 0 ? dx : 0.f);
            Wx[1] += (i0 == 1 ? w0 : 0.f) + (i1 == 1 ? dx : 0.f);
            Wx[2] += (i0 == 2 ? w0 : 0.f) + (i1 == 2 ? dx : 0.f);
            Wx[3] += (i1 == 3 ? dx : 0.f);
        }
    }

    float Wy[4] = {0.f, 0.f, 0.f, 0.f};
    int ymin = 0, nvh = 0;
    #pragma unroll
    for (int sh = 0; sh < SAMPLES; ++sh) {
        const float h = hstart + (float)sh * sub_h;
        if (h > -0.5f && h < (float)H_DIM - 0.5f) {
            const float hc = fminf(fmaxf(h, 0.0f), (float)(H_DIM - 1));
            const int y0 = (int)floorf(hc);
            const int y1 = min(y0 + 1, H_DIM - 1);
            const float dy = hc - (float)y0;
            if (nvh == 0) ymin = y0;
            ++nvh;
            const int i0 = y0 - ymin;
            const int i1 = y1 - ymin;
            const float w0 = 1.0f - dy;
            Wy[0] += (i0 == 0 ? w0 : 0.f) + (i1 == 0 ? dy : 0.f);
            Wy[1] += (i0 == 1 ? w0 : 0.f) + (i1 == 1 ? dy : 0.f);
            Wy[2] += (i0 == 2 ? w0 : 0.f) + (i1 == 2 ? dy : 0.f);
            Wy[3] += (i1 == 3 ? dy : 0.f);
        }
    }

    const int cnt = nvw * nvh;
    float4 res = make_float4(0.f, 0.f, 0.f, 0.f);

    if (cnt > 0) {
        const float4* baseb = src4 + (size_t)b * (H_DIM * W_DIM) * C4;
        float4 acc = make_float4(0.f, 0.f, 0.f, 0.f);
        #pragma unroll
        for (int iy = 0; iy < 4; ++iy) {
            if (Wy[iy] == 0.f) continue;           // wave-uniform, exact skip
            const int rowoff = (ymin + iy) * W_DIM + xmin;
            #pragma unroll
            for (int ix = 0; ix < 4; ++ix) {
                if (Wx[ix] == 0.f) continue;       // wave-uniform, exact skip
                const float wgt = Wy[iy] * Wx[ix];
                const float4 v = baseb[(size_t)(rowoff + ix) * C4 + lane];
                acc.x = fmaf(wgt, v.x, acc.x);
                acc.y = fmaf(wgt, v.y, acc.y);
                acc.z = fmaf(wgt, v.z, acc.z);
                acc.w = fmaf(wgt, v.w, acc.w);
            }
        }
        const float fc = (float)cnt;
        res = make_float4(acc.x / fc, acc.y / fc, acc.z / fc, acc.w / fc);
    }

    tmp4[(size_t)blk * 64 + lane] = res;   // [n][bin][c] coalesced 1 KB/wave
}

// ---------------------------------------------------------------------------
// tmp[n][bin][c] -> out[n][c][ph][pw]. Block = (channel-quarter q, n).
// Both global read and global write fully coalesced; LDS pad 65 avoids
// power-of-2 bank stride.
// ---------------------------------------------------------------------------
__global__ __launch_bounds__(256) void layout_out(const float* __restrict__ tmp,
                                                  float* __restrict__ out) {
    __shared__ float lds[BINS * 65];
    const int q = blockIdx.x;   // 0..3 -> channels q*64..q*64+63
    const int n = blockIdx.y;
    const int t = threadIdx.x;

    const float* tn = tmp + (size_t)n * BINS * C_DIM + q * 64;
    for (int j = t; j < BINS * 64; j += 256) {
        const int bin = j >> 6;
        const int c   = j & 63;
        lds[bin * 65 + c] = tn[(size_t)bin * C_DIM + c];
    }
    __syncthreads();
    float* on = out + (size_t)n * C_DIM * BINS + (size_t)q * 64 * BINS;
    for (int j = t; j < 64 * BINS; j += 256) {
        const int c   = j / BINS;
        const int bin = j - c * BINS;
        on[j] = lds[bin * 65 + c];
    }
}

// ---------------------------------------------------------------------------
// Fallback: block per (n,bin) x 256 ch, direct NCHW gather (only used if the
// harness workspace is too small for the staged path).
// ---------------------------------------------------------------------------
__global__ __launch_bounds__(256) void deform_roi_pool_nchw(const float* __restrict__ src,
                                                            const float* __restrict__ rois,
                                                            const float* __restrict__ offset,
                                                            float* __restrict__ out,
                                                            int N) {
    const int blk = blockIdx.x;
    const int n   = blk / BINS;
    const int bin = blk % BINS;
    const int ph  = bin / POOLED;
    const int pw  = bin % POOLED;
    const int c   = threadIdx.x;
    if (n >= N) return;

    const float* roi = rois + (size_t)n * 5;
    const int b = (int)roi[0];

    const float roi_sw = rintf(roi[1]) * SPATIAL_SCALE - 0.5f;
    const float roi_sh = rintf(roi[2]) * SPATIAL_SCALE - 0.5f;
    const float roi_ew = (rintf(roi[3]) + 1.0f) * SPATIAL_SCALE - 0.5f;
    const float roi_eh = (rintf(roi[4]) + 1.0f) * SPATIAL_SCALE - 0.5f;
    const float roi_w = fmaxf(roi_ew - roi_sw, 0.1f);
    const float roi_h = fmaxf(roi_eh - roi_sh, 0.1f);
    const float bin_w = roi_w / (float)POOLED;
    const float bin_h = roi_h / (float)POOLED;
    const float sub_w = bin_w / (float)SAMPLES;
    const float sub_h = bin_h / (float)SAMPLES;

    int part_h = (int)floorf(((float)ph / (float)POOLED) * (float)PART);
    int part_w = (int)floorf(((float)pw / (float)POOLED) * (float)PART);
    part_h = min(max(part_h, 0), PART - 1);
    part_w = min(max(part_w, 0), PART - 1);

    const float tx = offset[(((size_t)n * 2 + 0) * PART + part_h) * PART + part_w] * TRANS_STD;
    const float ty = offset[(((size_t)n * 2 + 1) * PART + part_h) * PART + part_w] * TRANS_STD;

    const float wstart = (float)pw * bin_w + roi_sw + tx * roi_w;
    const float hstart = (float)ph * bin_h + roi_sh + ty * roi_h;

    float sum = 0.0f;
    int cnt = 0;

    #pragma unroll
    for (int sh = 0; sh < SAMPLES; ++sh) {
        const float h = hstart + (float)sh * sub_h;
        #pragma unroll
        for (int sw = 0; sw < SAMPLES; ++sw) {
            const float w = wstart + (float)sw * sub_w;
            const bool valid = (w > -0.5f) && (w < (float)W_DIM - 0.5f) &&
                               (h > -0.5f) && (h < (float)H_DIM - 0.5f);
            if (!valid) continue;
            ++cnt;
            const float wc = fminf(fmaxf(w, 0.0f), (float)(W_DIM - 1));
            const float hc = fminf(fmaxf(h, 0.0f), (float)(H_DIM - 1));
            const int x0 = (int)floorf(wc);
            const int y0 = (int)floorf(hc);
            const int x1 = min(x0 + 1, W_DIM - 1);
            const int y1 = min(y0 + 1, H_DIM - 1);
            const float dx = wc - (float)x0;
            const float dy = hc - (float)y0;

            const size_t base = ((size_t)b * C_DIM + c) * (H_DIM * W_DIM);
            const float v00 = src[base + (size_t)y0 * W_DIM + x0];
            const float v01 = src[base + (size_t)y0 * W_DIM + x1];
            const float v10 = src[base + (size_t)y1 * W_DIM + x0];
            const float v11 = src[base + (size_t)y1 * W_DIM + x1];
            sum += (1.0f - dx) * (1.0f - dy) * v00
                 + (1.0f - dx) * dy          * v10
                 + dx          * (1.0f - dy) * v01
                 + dx          * dy          * v11;
        }
    }

    const float res = (cnt > 0) ? sum / (float)cnt : 0.0f;
    out[(((size_t)n * C_DIM + c) * POOLED + ph) * POOLED + pw] = res;
}

extern "C" void kernel_launch(void* const* d_in, const int* in_sizes, int n_in,
                              void* d_out, int out_size, void* d_ws, size_t ws_size,
                              hipStream_t stream) {
    const float* data   = (const float*)d_in[0];
    const float* rois   = (const float*)d_in[1];
    const float* offset = (const float*)d_in[2];
    float* out = (float*)d_out;
    const int N = in_sizes[1] / 5;

    const size_t nhwc_bytes = (size_t)B_DIM * C_DIM * H_DIM * W_DIM * sizeof(float);
    const size_t tmp_bytes  = (size_t)N * BINS * C_DIM * sizeof(float);

    if (ws_size >= nhwc_bytes + tmp_bytes) {
        float* data_t = (float*)d_ws;
        float* tmp    = (float*)((char*)d_ws + nhwc_bytes);
        dim3 tb(32, 8, 1);
        dim3 tg((H_DIM * W_DIM) / TS, C_DIM / TS, B_DIM);
        nchw_to_nhwc<<<tg, tb, 0, stream>>>(data, data_t);
        deform_roi_pool_v3<<<N * BINS, 64, 0, stream>>>(
            (const float4*)data_t, rois, offset, (float4*)tmp, N);
        layout_out<<<dim3(4, N, 1), 256, 0, stream>>>(tmp, out);
    } else {
        deform_roi_pool_nchw<<<N * BINS, C_DIM, 0, stream>>>(
            data, rois, offset, out, N);
    }
}